// Round 1
// baseline (1036.291 us; speedup 1.0000x reference)
//
#include <hip/hip_runtime.h>

#define N_NODES   100000
#define N_EDGES   1600000
#define D         128
#define NUM_GRAPHS 128

#define SCAN_ITEMS 1024   // items per scan block (256 thr x 4)
#define GEMM_ROWS  64
#define XS_STRIDE  260    // 128 self + 128 neigh + 4 pad floats

// ---------------- CSR build ----------------

__global__ void k_edge_deg(const int* __restrict__ dst, int* __restrict__ deg) {
    int e = blockIdx.x * blockDim.x + threadIdx.x;
    if (e < N_EDGES) atomicAdd(&deg[dst[e]], 1);
}

__global__ void k_gcnt(const int* __restrict__ gid, int* __restrict__ gcnt) {
    int n = blockIdx.x * blockDim.x + threadIdx.x;
    if (n < N_NODES) atomicAdd(&gcnt[gid[n]], 1);
}

__global__ void k_scan1(const int* __restrict__ deg, int* __restrict__ bsum) {
    __shared__ int sh[256];
    int base = blockIdx.x * SCAN_ITEMS + threadIdx.x * 4;
    int s = 0;
#pragma unroll
    for (int i = 0; i < 4; ++i) {
        int idx = base + i;
        if (idx < N_NODES) s += deg[idx];
    }
    sh[threadIdx.x] = s;
    __syncthreads();
    for (int off = 128; off > 0; off >>= 1) {
        if (threadIdx.x < off) sh[threadIdx.x] += sh[threadIdx.x + off];
        __syncthreads();
    }
    if (threadIdx.x == 0) bsum[blockIdx.x] = sh[0];
}

__global__ void k_scan2(int* __restrict__ bsum, int* __restrict__ row_start, int nb) {
    if (threadIdx.x == 0 && blockIdx.x == 0) {
        int run = 0;
        for (int i = 0; i < nb; ++i) { int t = bsum[i]; bsum[i] = run; run += t; }
        row_start[N_NODES] = run;
    }
}

__global__ void k_scan3(const int* __restrict__ deg, const int* __restrict__ bsum,
                        int* __restrict__ row_start) {
    __shared__ int sh[256];
    int t = threadIdx.x;
    int base = blockIdx.x * SCAN_ITEMS + t * 4;
    int v[4]; int s = 0;
#pragma unroll
    for (int i = 0; i < 4; ++i) {
        int idx = base + i;
        v[i] = (idx < N_NODES) ? deg[idx] : 0;
        s += v[i];
    }
    sh[t] = s;
    __syncthreads();
    // Hillis-Steele inclusive scan over 256 thread sums
    for (int off = 1; off < 256; off <<= 1) {
        int add = (t >= off) ? sh[t - off] : 0;
        __syncthreads();
        sh[t] += add;
        __syncthreads();
    }
    int excl = ((t > 0) ? sh[t - 1] : 0) + bsum[blockIdx.x];
#pragma unroll
    for (int i = 0; i < 4; ++i) {
        int idx = base + i;
        if (idx < N_NODES) { row_start[idx] = excl; excl += v[i]; }
    }
}

__global__ void k_fill(const int* __restrict__ src, const int* __restrict__ dst,
                       const int* __restrict__ row_start, int* __restrict__ cursor,
                       int* __restrict__ adj) {
    int e = blockIdx.x * blockDim.x + threadIdx.x;
    if (e < N_EDGES) {
        int d = dst[e];
        int pos = atomicAdd(&cursor[d], 1);
        adj[row_start[d] + pos] = src[e];
    }
}

// ---------------- mean aggregation (gather-reduce over CSR) ----------------
// 256 threads = 8 nodes/block, 32 lanes per node, each lane owns one float4 (4 cols)
__global__ void k_agg(const float* __restrict__ hin, const int* __restrict__ row_start,
                      const int* __restrict__ adj, float* __restrict__ hout) {
    int node = blockIdx.x * 8 + (threadIdx.x >> 5);
    int lane = threadIdx.x & 31;
    if (node >= N_NODES) return;
    int beg = row_start[node], end = row_start[node + 1];
    const float4* hv = (const float4*)hin;
    float4 acc = make_float4(0.f, 0.f, 0.f, 0.f);
    int j = beg;
    for (; j + 3 < end; j += 4) {
        int s0 = adj[j], s1 = adj[j + 1], s2 = adj[j + 2], s3 = adj[j + 3];
        float4 v0 = hv[s0 * 32 + lane];
        float4 v1 = hv[s1 * 32 + lane];
        float4 v2 = hv[s2 * 32 + lane];
        float4 v3 = hv[s3 * 32 + lane];
        acc.x += v0.x + v1.x + v2.x + v3.x;
        acc.y += v0.y + v1.y + v2.y + v3.y;
        acc.z += v0.z + v1.z + v2.z + v3.z;
        acc.w += v0.w + v1.w + v2.w + v3.w;
    }
    for (; j < end; ++j) {
        int s = adj[j];
        float4 v = hv[s * 32 + lane];
        acc.x += v.x; acc.y += v.y; acc.z += v.z; acc.w += v.w;
    }
    int degn = end - beg;
    float inv = (degn > 0) ? (1.0f / (float)degn) : 0.0f;
    acc.x *= inv; acc.y *= inv; acc.z *= inv; acc.w *= inv;
    ((float4*)hout)[node * 32 + lane] = acc;
}

// ---------------- fused GEMM: out = relu([X0|X1] @ [Ws;Wn] + b) ----------------
// Block: 256 threads; 64 rows x 128 cols tile; K=256. X staged in LDS row-major.
// POOL=1: instead of writing rows, run-compress by graph id and atomicAdd to gsum.
template <int POOL>
__global__ __launch_bounds__(256) void k_gemm(
    const float* __restrict__ X0, const float* __restrict__ X1,
    const float* __restrict__ Ws, const float* __restrict__ Wn,
    const float* __restrict__ bias, float* __restrict__ out,
    const int* __restrict__ gid, float* __restrict__ gsum) {
    __shared__ float XS[GEMM_ROWS][XS_STRIDE];
    const int t = threadIdx.x;
    const int row0 = blockIdx.x * GEMM_ROWS;
    // ---- stage X tile: rows row0..row0+63, cols 0..127 (self) | 128..255 (neigh)
    {
        const int chunk = t & 31;   // float4 col chunk
        const int rsub  = t >> 5;   // 0..7
        const float4* X0v = (const float4*)X0;
        const float4* X1v = (const float4*)X1;
#pragma unroll
        for (int i = 0; i < 8; ++i) {
            int r = i * 8 + rsub;
            int row = row0 + r;
            float4 a, b;
            if (row < N_NODES) {
                a = X0v[row * 32 + chunk];
                b = X1v[row * 32 + chunk];
            } else {
                a = make_float4(0.f, 0.f, 0.f, 0.f);
                b = a;
            }
            *(float4*)&XS[r][chunk * 4]       = a;
            *(float4*)&XS[r][128 + chunk * 4] = b;
        }
    }
    __syncthreads();

    const int tc = t & 31;   // cols 4*tc .. 4*tc+3
    const int tr = t >> 5;   // rows tr*8 .. tr*8+7
    float4 acc[8];
#pragma unroll
    for (int i = 0; i < 8; ++i) acc[i] = make_float4(0.f, 0.f, 0.f, 0.f);

    const float4* Wsv = (const float4*)Ws;
    const float4* Wnv = (const float4*)Wn;

    // self half: k = 0..127
#pragma unroll 4
    for (int kq = 0; kq < 32; ++kq) {
        float4 w0 = Wsv[(4 * kq + 0) * 32 + tc];
        float4 w1 = Wsv[(4 * kq + 1) * 32 + tc];
        float4 w2 = Wsv[(4 * kq + 2) * 32 + tc];
        float4 w3 = Wsv[(4 * kq + 3) * 32 + tc];
#pragma unroll
        for (int i = 0; i < 8; ++i) {
            const float4 x = *(const float4*)&XS[tr * 8 + i][4 * kq];
            acc[i].x += x.x * w0.x + x.y * w1.x + x.z * w2.x + x.w * w3.x;
            acc[i].y += x.x * w0.y + x.y * w1.y + x.z * w2.y + x.w * w3.y;
            acc[i].z += x.x * w0.z + x.y * w1.z + x.z * w2.z + x.w * w3.z;
            acc[i].w += x.x * w0.w + x.y * w1.w + x.z * w2.w + x.w * w3.w;
        }
    }
    // neigh half: k = 128..255
#pragma unroll 4
    for (int kq = 0; kq < 32; ++kq) {
        float4 w0 = Wnv[(4 * kq + 0) * 32 + tc];
        float4 w1 = Wnv[(4 * kq + 1) * 32 + tc];
        float4 w2 = Wnv[(4 * kq + 2) * 32 + tc];
        float4 w3 = Wnv[(4 * kq + 3) * 32 + tc];
#pragma unroll
        for (int i = 0; i < 8; ++i) {
            const float4 x = *(const float4*)&XS[tr * 8 + i][128 + 4 * kq];
            acc[i].x += x.x * w0.x + x.y * w1.x + x.z * w2.x + x.w * w3.x;
            acc[i].y += x.x * w0.y + x.y * w1.y + x.z * w2.y + x.w * w3.y;
            acc[i].z += x.x * w0.z + x.y * w1.z + x.z * w2.z + x.w * w3.z;
            acc[i].w += x.x * w0.w + x.y * w1.w + x.z * w2.w + x.w * w3.w;
        }
    }

    const float4 bia = ((const float4*)bias)[tc];
    if (POOL) {
        float4 run = make_float4(0.f, 0.f, 0.f, 0.f);
        int curg = -1;
#pragma unroll
        for (int i = 0; i < 8; ++i) {
            int row = row0 + tr * 8 + i;
            if (row >= N_NODES) break;
            float4 v;
            v.x = fmaxf(acc[i].x + bia.x, 0.f);
            v.y = fmaxf(acc[i].y + bia.y, 0.f);
            v.z = fmaxf(acc[i].z + bia.z, 0.f);
            v.w = fmaxf(acc[i].w + bia.w, 0.f);
            int g = gid[row];
            if (g != curg) {
                if (curg >= 0) {
                    float* gp = gsum + curg * D + 4 * tc;
                    atomicAdd(gp + 0, run.x);
                    atomicAdd(gp + 1, run.y);
                    atomicAdd(gp + 2, run.z);
                    atomicAdd(gp + 3, run.w);
                }
                curg = g; run = v;
            } else {
                run.x += v.x; run.y += v.y; run.z += v.z; run.w += v.w;
            }
        }
        if (curg >= 0) {
            float* gp = gsum + curg * D + 4 * tc;
            atomicAdd(gp + 0, run.x);
            atomicAdd(gp + 1, run.y);
            atomicAdd(gp + 2, run.z);
            atomicAdd(gp + 3, run.w);
        }
    } else {
#pragma unroll
        for (int i = 0; i < 8; ++i) {
            int row = row0 + tr * 8 + i;
            if (row < N_NODES) {
                float4 v;
                v.x = fmaxf(acc[i].x + bia.x, 0.f);
                v.y = fmaxf(acc[i].y + bia.y, 0.f);
                v.z = fmaxf(acc[i].z + bia.z, 0.f);
                v.w = fmaxf(acc[i].w + bia.w, 0.f);
                ((float4*)out)[row * 32 + tc] = v;
            }
        }
    }
}

// ---------------- final divide ----------------
__global__ void k_final(const float* __restrict__ gsum, const int* __restrict__ gcnt,
                        float* __restrict__ out) {
    int i = blockIdx.x * blockDim.x + threadIdx.x;
    if (i < NUM_GRAPHS * D) {
        int g = i >> 7;
        int c = gcnt[g];
        out[i] = gsum[i] / (float)(c > 0 ? c : 1);
    }
}

// ---------------- launch ----------------
extern "C" void kernel_launch(void* const* d_in, const int* in_sizes, int n_in,
                              void* d_out, int out_size, void* d_ws, size_t ws_size,
                              hipStream_t stream) {
    const float* h   = (const float*)d_in[0];
    const float* W1s = (const float*)d_in[1];
    const float* W1n = (const float*)d_in[2];
    const float* b1  = (const float*)d_in[3];
    const float* W2s = (const float*)d_in[4];
    const float* W2n = (const float*)d_in[5];
    const float* b2  = (const float*)d_in[6];
    const int* src   = (const int*)d_in[7];
    const int* dst   = (const int*)d_in[8];
    const int* gids  = (const int*)d_in[9];
    float* out = (float*)d_out;
    char* ws = (char*)d_ws;

    size_t off = 0;
    auto alloc = [&](size_t bytes) {
        size_t o = off;
        off = (off + bytes + 255) & ~(size_t)255;
        return o;
    };
    // zeroed region (one memset)
    size_t z0         = off;
    size_t deg_off    = alloc((size_t)N_NODES * 4);
    size_t cursor_off = alloc((size_t)N_NODES * 4);
    size_t gcnt_off   = alloc((size_t)NUM_GRAPHS * 4);
    size_t gsum_off   = alloc((size_t)NUM_GRAPHS * D * 4);
    size_t bsum_off   = alloc(128 * 4);
    size_t zlen       = off - z0;
    size_t rs_off     = alloc((size_t)(N_NODES + 1) * 4);
    size_t adj_off    = alloc((size_t)N_EDGES * 4);
    size_t hn_off     = alloc((size_t)N_NODES * D * 4);
    size_t h1_off     = alloc((size_t)N_NODES * D * 4);
    (void)ws_size;

    int*   deg       = (int*)(ws + deg_off);
    int*   cursor    = (int*)(ws + cursor_off);
    int*   gcnt      = (int*)(ws + gcnt_off);
    float* gsum      = (float*)(ws + gsum_off);
    int*   bsum      = (int*)(ws + bsum_off);
    int*   row_start = (int*)(ws + rs_off);
    int*   adj       = (int*)(ws + adj_off);
    float* hn        = (float*)(ws + hn_off);
    float* h1        = (float*)(ws + h1_off);

    hipMemsetAsync(ws + z0, 0, zlen, stream);

    const int nb_scan = (N_NODES + SCAN_ITEMS - 1) / SCAN_ITEMS;  // 98

    k_edge_deg<<<(N_EDGES + 255) / 256, 256, 0, stream>>>(dst, deg);
    k_gcnt<<<(N_NODES + 255) / 256, 256, 0, stream>>>(gids, gcnt);
    k_scan1<<<nb_scan, 256, 0, stream>>>(deg, bsum);
    k_scan2<<<1, 64, 0, stream>>>(bsum, row_start, nb_scan);
    k_scan3<<<nb_scan, 256, 0, stream>>>(deg, bsum, row_start);
    k_fill<<<(N_EDGES + 255) / 256, 256, 0, stream>>>(src, dst, row_start, cursor, adj);

    const int gemm_blocks = (N_NODES + GEMM_ROWS - 1) / GEMM_ROWS;  // 1563

    // layer 1
    k_agg<<<(N_NODES + 7) / 8, 256, 0, stream>>>(h, row_start, adj, hn);
    k_gemm<0><<<gemm_blocks, 256, 0, stream>>>(h, hn, W1s, W1n, b1, h1, nullptr, nullptr);
    // layer 2 (pool fused into epilogue)
    k_agg<<<(N_NODES + 7) / 8, 256, 0, stream>>>(h1, row_start, adj, hn);
    k_gemm<1><<<gemm_blocks, 256, 0, stream>>>(h1, hn, W2s, W2n, b2, nullptr, gids, gsum);

    k_final<<<(NUM_GRAPHS * D + 255) / 256, 256, 0, stream>>>(gsum, gcnt, out);
}

// Round 2
// 775.103 us; speedup vs baseline: 1.3370x; 1.3370x over previous
//
#include <hip/hip_runtime.h>

#define N_NODES   100000
#define N_EDGES   1600000
#define D         128
#define NUM_GRAPHS 128

#define SCAN_ITEMS 1024   // items per scan block (256 thr x 4)
#define GEMM_ROWS  64
#define XS_STRIDE  260    // 128 self + 128 neigh + 4 pad floats

// ---------------- CSR build ----------------

__global__ void k_edge_deg(const int* __restrict__ dst, int* __restrict__ deg) {
    int e = blockIdx.x * blockDim.x + threadIdx.x;
    if (e < N_EDGES) atomicAdd(&deg[dst[e]], 1);
}

// graph_ids is SORTED -> per-graph count via binary search, no atomics.
__global__ void k_gcnt_bs(const int* __restrict__ gid, int* __restrict__ gcnt) {
    int g = threadIdx.x;
    if (g >= NUM_GRAPHS) return;
    int lo = 0, hi = N_NODES;
    while (lo < hi) { int mid = (lo + hi) >> 1; if (gid[mid] < g) lo = mid + 1; else hi = mid; }
    int beg = lo;
    hi = N_NODES;
    while (lo < hi) { int mid = (lo + hi) >> 1; if (gid[mid] < g + 1) lo = mid + 1; else hi = mid; }
    gcnt[g] = lo - beg;
}

__global__ void k_scan1(const int* __restrict__ deg, int* __restrict__ bsum) {
    __shared__ int sh[256];
    int base = blockIdx.x * SCAN_ITEMS + threadIdx.x * 4;
    int s = 0;
#pragma unroll
    for (int i = 0; i < 4; ++i) {
        int idx = base + i;
        if (idx < N_NODES) s += deg[idx];
    }
    sh[threadIdx.x] = s;
    __syncthreads();
    for (int off = 128; off > 0; off >>= 1) {
        if (threadIdx.x < off) sh[threadIdx.x] += sh[threadIdx.x + off];
        __syncthreads();
    }
    if (threadIdx.x == 0) bsum[blockIdx.x] = sh[0];
}

__global__ void k_scan2(int* __restrict__ bsum, int* __restrict__ row_start, int nb) {
    if (threadIdx.x == 0 && blockIdx.x == 0) {
        int run = 0;
        for (int i = 0; i < nb; ++i) { int t = bsum[i]; bsum[i] = run; run += t; }
        row_start[N_NODES] = run;
    }
}

__global__ void k_scan3(const int* __restrict__ deg, const int* __restrict__ bsum,
                        int* __restrict__ row_start) {
    __shared__ int sh[256];
    int t = threadIdx.x;
    int base = blockIdx.x * SCAN_ITEMS + t * 4;
    int v[4]; int s = 0;
#pragma unroll
    for (int i = 0; i < 4; ++i) {
        int idx = base + i;
        v[i] = (idx < N_NODES) ? deg[idx] : 0;
        s += v[i];
    }
    sh[t] = s;
    __syncthreads();
    // Hillis-Steele inclusive scan over 256 thread sums
    for (int off = 1; off < 256; off <<= 1) {
        int add = (t >= off) ? sh[t - off] : 0;
        __syncthreads();
        sh[t] += add;
        __syncthreads();
    }
    int excl = ((t > 0) ? sh[t - 1] : 0) + bsum[blockIdx.x];
#pragma unroll
    for (int i = 0; i < 4; ++i) {
        int idx = base + i;
        if (idx < N_NODES) { row_start[idx] = excl; excl += v[i]; }
    }
}

__global__ void k_fill(const int* __restrict__ src, const int* __restrict__ dst,
                       const int* __restrict__ row_start, int* __restrict__ cursor,
                       int* __restrict__ adj) {
    int e = blockIdx.x * blockDim.x + threadIdx.x;
    if (e < N_EDGES) {
        int d = dst[e];
        int pos = atomicAdd(&cursor[d], 1);
        adj[row_start[d] + pos] = src[e];
    }
}

// ---------------- mean aggregation (gather-reduce over CSR) ----------------
// 256 threads = 8 nodes/block, 32 lanes per node, each lane owns one float4 (4 cols)
__global__ void k_agg(const float* __restrict__ hin, const int* __restrict__ row_start,
                      const int* __restrict__ adj, float* __restrict__ hout) {
    int node = blockIdx.x * 8 + (threadIdx.x >> 5);
    int lane = threadIdx.x & 31;
    if (node >= N_NODES) return;
    int beg = row_start[node], end = row_start[node + 1];
    const float4* hv = (const float4*)hin;
    float4 acc = make_float4(0.f, 0.f, 0.f, 0.f);
    int j = beg;
    for (; j + 3 < end; j += 4) {
        int s0 = adj[j], s1 = adj[j + 1], s2 = adj[j + 2], s3 = adj[j + 3];
        float4 v0 = hv[s0 * 32 + lane];
        float4 v1 = hv[s1 * 32 + lane];
        float4 v2 = hv[s2 * 32 + lane];
        float4 v3 = hv[s3 * 32 + lane];
        acc.x += v0.x + v1.x + v2.x + v3.x;
        acc.y += v0.y + v1.y + v2.y + v3.y;
        acc.z += v0.z + v1.z + v2.z + v3.z;
        acc.w += v0.w + v1.w + v2.w + v3.w;
    }
    for (; j < end; ++j) {
        int s = adj[j];
        float4 v = hv[s * 32 + lane];
        acc.x += v.x; acc.y += v.y; acc.z += v.z; acc.w += v.w;
    }
    int degn = end - beg;
    float inv = (degn > 0) ? (1.0f / (float)degn) : 0.0f;
    acc.x *= inv; acc.y *= inv; acc.z *= inv; acc.w *= inv;
    ((float4*)hout)[node * 32 + lane] = acc;
}

// ---------------- fused GEMM: out = relu([X0|X1] @ [Ws;Wn] + b) ----------------
// Block: 256 threads; 64 rows x 128 cols tile; K=256. X staged in LDS row-major.
// POOL=1: instead of writing rows, run-compress by graph id and atomicAdd to gsum.
template <int POOL>
__global__ __launch_bounds__(256) void k_gemm(
    const float* __restrict__ X0, const float* __restrict__ X1,
    const float* __restrict__ Ws, const float* __restrict__ Wn,
    const float* __restrict__ bias, float* __restrict__ out,
    const int* __restrict__ gid, float* __restrict__ gsum) {
    __shared__ float XS[GEMM_ROWS][XS_STRIDE];
    const int t = threadIdx.x;
    const int row0 = blockIdx.x * GEMM_ROWS;
    // ---- stage X tile: rows row0..row0+63, cols 0..127 (self) | 128..255 (neigh)
    {
        const int chunk = t & 31;   // float4 col chunk
        const int rsub  = t >> 5;   // 0..7
        const float4* X0v = (const float4*)X0;
        const float4* X1v = (const float4*)X1;
#pragma unroll
        for (int i = 0; i < 8; ++i) {
            int r = i * 8 + rsub;
            int row = row0 + r;
            float4 a, b;
            if (row < N_NODES) {
                a = X0v[row * 32 + chunk];
                b = X1v[row * 32 + chunk];
            } else {
                a = make_float4(0.f, 0.f, 0.f, 0.f);
                b = a;
            }
            *(float4*)&XS[r][chunk * 4]       = a;
            *(float4*)&XS[r][128 + chunk * 4] = b;
        }
    }
    __syncthreads();

    const int tc = t & 31;   // cols 4*tc .. 4*tc+3
    const int tr = t >> 5;   // rows tr*8 .. tr*8+7
    float4 acc[8];
#pragma unroll
    for (int i = 0; i < 8; ++i) acc[i] = make_float4(0.f, 0.f, 0.f, 0.f);

    const float4* Wsv = (const float4*)Ws;
    const float4* Wnv = (const float4*)Wn;

    // self half: k = 0..127
#pragma unroll 4
    for (int kq = 0; kq < 32; ++kq) {
        float4 w0 = Wsv[(4 * kq + 0) * 32 + tc];
        float4 w1 = Wsv[(4 * kq + 1) * 32 + tc];
        float4 w2 = Wsv[(4 * kq + 2) * 32 + tc];
        float4 w3 = Wsv[(4 * kq + 3) * 32 + tc];
#pragma unroll
        for (int i = 0; i < 8; ++i) {
            const float4 x = *(const float4*)&XS[tr * 8 + i][4 * kq];
            acc[i].x += x.x * w0.x + x.y * w1.x + x.z * w2.x + x.w * w3.x;
            acc[i].y += x.x * w0.y + x.y * w1.y + x.z * w2.y + x.w * w3.y;
            acc[i].z += x.x * w0.z + x.y * w1.z + x.z * w2.z + x.w * w3.z;
            acc[i].w += x.x * w0.w + x.y * w1.w + x.z * w2.w + x.w * w3.w;
        }
    }
    // neigh half: k = 128..255
#pragma unroll 4
    for (int kq = 0; kq < 32; ++kq) {
        float4 w0 = Wnv[(4 * kq + 0) * 32 + tc];
        float4 w1 = Wnv[(4 * kq + 1) * 32 + tc];
        float4 w2 = Wnv[(4 * kq + 2) * 32 + tc];
        float4 w3 = Wnv[(4 * kq + 3) * 32 + tc];
#pragma unroll
        for (int i = 0; i < 8; ++i) {
            const float4 x = *(const float4*)&XS[tr * 8 + i][128 + 4 * kq];
            acc[i].x += x.x * w0.x + x.y * w1.x + x.z * w2.x + x.w * w3.x;
            acc[i].y += x.x * w0.y + x.y * w1.y + x.z * w2.y + x.w * w3.y;
            acc[i].z += x.x * w0.z + x.y * w1.z + x.z * w2.z + x.w * w3.z;
            acc[i].w += x.x * w0.w + x.y * w1.w + x.z * w2.w + x.w * w3.w;
        }
    }

    const float4 bia = ((const float4*)bias)[tc];
    if (POOL) {
        float4 run = make_float4(0.f, 0.f, 0.f, 0.f);
        int curg = -1;
#pragma unroll
        for (int i = 0; i < 8; ++i) {
            int row = row0 + tr * 8 + i;
            if (row >= N_NODES) break;
            float4 v;
            v.x = fmaxf(acc[i].x + bia.x, 0.f);
            v.y = fmaxf(acc[i].y + bia.y, 0.f);
            v.z = fmaxf(acc[i].z + bia.z, 0.f);
            v.w = fmaxf(acc[i].w + bia.w, 0.f);
            int g = gid[row];
            if (g != curg) {
                if (curg >= 0) {
                    float* gp = gsum + curg * D + 4 * tc;
                    atomicAdd(gp + 0, run.x);
                    atomicAdd(gp + 1, run.y);
                    atomicAdd(gp + 2, run.z);
                    atomicAdd(gp + 3, run.w);
                }
                curg = g; run = v;
            } else {
                run.x += v.x; run.y += v.y; run.z += v.z; run.w += v.w;
            }
        }
        if (curg >= 0) {
            float* gp = gsum + curg * D + 4 * tc;
            atomicAdd(gp + 0, run.x);
            atomicAdd(gp + 1, run.y);
            atomicAdd(gp + 2, run.z);
            atomicAdd(gp + 3, run.w);
        }
    } else {
#pragma unroll
        for (int i = 0; i < 8; ++i) {
            int row = row0 + tr * 8 + i;
            if (row < N_NODES) {
                float4 v;
                v.x = fmaxf(acc[i].x + bia.x, 0.f);
                v.y = fmaxf(acc[i].y + bia.y, 0.f);
                v.z = fmaxf(acc[i].z + bia.z, 0.f);
                v.w = fmaxf(acc[i].w + bia.w, 0.f);
                ((float4*)out)[row * 32 + tc] = v;
            }
        }
    }
}

// ---------------- final divide ----------------
__global__ void k_final(const float* __restrict__ gsum, const int* __restrict__ gcnt,
                        float* __restrict__ out) {
    int i = blockIdx.x * blockDim.x + threadIdx.x;
    if (i < NUM_GRAPHS * D) {
        int g = i >> 7;
        int c = gcnt[g];
        out[i] = gsum[i] / (float)(c > 0 ? c : 1);
    }
}

// ---------------- launch ----------------
extern "C" void kernel_launch(void* const* d_in, const int* in_sizes, int n_in,
                              void* d_out, int out_size, void* d_ws, size_t ws_size,
                              hipStream_t stream) {
    const float* h   = (const float*)d_in[0];
    const float* W1s = (const float*)d_in[1];
    const float* W1n = (const float*)d_in[2];
    const float* b1  = (const float*)d_in[3];
    const float* W2s = (const float*)d_in[4];
    const float* W2n = (const float*)d_in[5];
    const float* b2  = (const float*)d_in[6];
    const int* src   = (const int*)d_in[7];
    const int* dst   = (const int*)d_in[8];
    const int* gids  = (const int*)d_in[9];
    float* out = (float*)d_out;
    char* ws = (char*)d_ws;

    size_t off = 0;
    auto alloc = [&](size_t bytes) {
        size_t o = off;
        off = (off + bytes + 255) & ~(size_t)255;
        return o;
    };
    // zeroed region (one memset)
    size_t z0         = off;
    size_t deg_off    = alloc((size_t)N_NODES * 4);
    size_t cursor_off = alloc((size_t)N_NODES * 4);
    size_t gsum_off   = alloc((size_t)NUM_GRAPHS * D * 4);
    size_t bsum_off   = alloc(128 * 4);
    size_t zlen       = off - z0;
    size_t gcnt_off   = alloc((size_t)NUM_GRAPHS * 4);
    size_t rs_off     = alloc((size_t)(N_NODES + 1) * 4);
    size_t adj_off    = alloc((size_t)N_EDGES * 4);
    size_t hn_off     = alloc((size_t)N_NODES * D * 4);
    size_t h1_off     = alloc((size_t)N_NODES * D * 4);
    (void)ws_size;

    int*   deg       = (int*)(ws + deg_off);
    int*   cursor    = (int*)(ws + cursor_off);
    int*   gcnt      = (int*)(ws + gcnt_off);
    float* gsum      = (float*)(ws + gsum_off);
    int*   bsum      = (int*)(ws + bsum_off);
    int*   row_start = (int*)(ws + rs_off);
    int*   adj       = (int*)(ws + adj_off);
    float* hn        = (float*)(ws + hn_off);
    float* h1        = (float*)(ws + h1_off);

    hipMemsetAsync(ws + z0, 0, zlen, stream);

    const int nb_scan = (N_NODES + SCAN_ITEMS - 1) / SCAN_ITEMS;  // 98

    k_edge_deg<<<(N_EDGES + 255) / 256, 256, 0, stream>>>(dst, deg);
    k_gcnt_bs<<<1, 128, 0, stream>>>(gids, gcnt);
    k_scan1<<<nb_scan, 256, 0, stream>>>(deg, bsum);
    k_scan2<<<1, 64, 0, stream>>>(bsum, row_start, nb_scan);
    k_scan3<<<nb_scan, 256, 0, stream>>>(deg, bsum, row_start);
    k_fill<<<(N_EDGES + 255) / 256, 256, 0, stream>>>(src, dst, row_start, cursor, adj);

    const int gemm_blocks = (N_NODES + GEMM_ROWS - 1) / GEMM_ROWS;  // 1563

    // layer 1
    k_agg<<<(N_NODES + 7) / 8, 256, 0, stream>>>(h, row_start, adj, hn);
    k_gemm<0><<<gemm_blocks, 256, 0, stream>>>(h, hn, W1s, W1n, b1, h1, nullptr, nullptr);
    // layer 2 (pool fused into epilogue)
    k_agg<<<(N_NODES + 7) / 8, 256, 0, stream>>>(h1, row_start, adj, hn);
    k_gemm<1><<<gemm_blocks, 256, 0, stream>>>(h1, hn, W2s, W2n, b2, nullptr, gids, gsum);

    k_final<<<(NUM_GRAPHS * D + 255) / 256, 256, 0, stream>>>(gsum, gcnt, out);
}

// Round 3
// 526.616 us; speedup vs baseline: 1.9678x; 1.4719x over previous
//
#include <hip/hip_runtime.h>

#define N_NODES   100000
#define N_EDGES   1600000
#define D         128
#define NUM_GRAPHS 128

#define SCAN_ITEMS 1024   // items per scan block (256 thr x 4)

typedef __attribute__((ext_vector_type(8))) short   bf16x8;
typedef __attribute__((ext_vector_type(8))) unsigned short u16x8;
typedef __attribute__((ext_vector_type(4))) float   f32x4;

__device__ __forceinline__ float bf2f(unsigned short v) {
    return __uint_as_float(((unsigned int)v) << 16);
}
__device__ __forceinline__ unsigned short f2bf(float f) {
    unsigned int u = __float_as_uint(f);
    u = (u + 0x7FFFu + ((u >> 16) & 1u)) >> 16;
    return (unsigned short)u;
}

// ---------------- CSR build ----------------

__global__ void k_edge_deg(const int* __restrict__ dst, int* __restrict__ deg) {
    int e = blockIdx.x * blockDim.x + threadIdx.x;
    if (e < N_EDGES) atomicAdd(&deg[dst[e]], 1);
}

// graph_ids is SORTED -> per-graph count via binary search, no atomics.
__global__ void k_gcnt_bs(const int* __restrict__ gid, int* __restrict__ gcnt) {
    int g = threadIdx.x;
    if (g >= NUM_GRAPHS) return;
    int lo = 0, hi = N_NODES;
    while (lo < hi) { int mid = (lo + hi) >> 1; if (gid[mid] < g) lo = mid + 1; else hi = mid; }
    int beg = lo;
    hi = N_NODES;
    while (lo < hi) { int mid = (lo + hi) >> 1; if (gid[mid] < g + 1) lo = mid + 1; else hi = mid; }
    gcnt[g] = lo - beg;
}

__global__ void k_scan1(const int* __restrict__ deg, int* __restrict__ bsum) {
    __shared__ int sh[256];
    int base = blockIdx.x * SCAN_ITEMS + threadIdx.x * 4;
    int s = 0;
#pragma unroll
    for (int i = 0; i < 4; ++i) {
        int idx = base + i;
        if (idx < N_NODES) s += deg[idx];
    }
    sh[threadIdx.x] = s;
    __syncthreads();
    for (int off = 128; off > 0; off >>= 1) {
        if (threadIdx.x < off) sh[threadIdx.x] += sh[threadIdx.x + off];
        __syncthreads();
    }
    if (threadIdx.x == 0) bsum[blockIdx.x] = sh[0];
}

__global__ void k_scan2(int* __restrict__ bsum, int* __restrict__ row_start, int nb) {
    if (threadIdx.x == 0 && blockIdx.x == 0) {
        int run = 0;
        for (int i = 0; i < nb; ++i) { int t = bsum[i]; bsum[i] = run; run += t; }
        row_start[N_NODES] = run;
    }
}

__global__ void k_scan3(const int* __restrict__ deg, const int* __restrict__ bsum,
                        int* __restrict__ row_start) {
    __shared__ int sh[256];
    int t = threadIdx.x;
    int base = blockIdx.x * SCAN_ITEMS + t * 4;
    int v[4]; int s = 0;
#pragma unroll
    for (int i = 0; i < 4; ++i) {
        int idx = base + i;
        v[i] = (idx < N_NODES) ? deg[idx] : 0;
        s += v[i];
    }
    sh[t] = s;
    __syncthreads();
    for (int off = 1; off < 256; off <<= 1) {
        int add = (t >= off) ? sh[t - off] : 0;
        __syncthreads();
        sh[t] += add;
        __syncthreads();
    }
    int excl = ((t > 0) ? sh[t - 1] : 0) + bsum[blockIdx.x];
#pragma unroll
    for (int i = 0; i < 4; ++i) {
        int idx = base + i;
        if (idx < N_NODES) { row_start[idx] = excl; excl += v[i]; }
    }
}

__global__ void k_fill(const int* __restrict__ src, const int* __restrict__ dst,
                       const int* __restrict__ row_start, int* __restrict__ cursor,
                       int* __restrict__ adj) {
    int e = blockIdx.x * blockDim.x + threadIdx.x;
    if (e < N_EDGES) {
        int d = dst[e];
        int pos = atomicAdd(&cursor[d], 1);
        adj[row_start[d] + pos] = src[e];
    }
}

// ---------------- casts / weight prep ----------------

// h fp32 [N,128] -> bf16
__global__ void k_cast_h(const float* __restrict__ h, unsigned short* __restrict__ hb) {
    int i = blockIdx.x * 256 + threadIdx.x;          // one thread = 8 elems
    if (i >= N_NODES * (D / 8)) return;
    const float4* hv = (const float4*)h;
    float4 x = hv[2 * i], y = hv[2 * i + 1];
    u16x8 p;
    p[0] = f2bf(x.x); p[1] = f2bf(x.y); p[2] = f2bf(x.z); p[3] = f2bf(x.w);
    p[4] = f2bf(y.x); p[5] = f2bf(y.y); p[6] = f2bf(y.z); p[7] = f2bf(y.w);
    *(u16x8*)(hb + (size_t)i * 8) = p;
}

// Wt1[n][k] (k<128: W1s[k][n], else W1n[k-128][n]) -> [128][256] bf16
__global__ void k_prep_w1(const float* __restrict__ Ws, const float* __restrict__ Wn,
                          unsigned short* __restrict__ Wt) {
    int idx = blockIdx.x * 256 + threadIdx.x;  // 32768
    if (idx >= D * 256) return;
    int n = idx >> 8, k = idx & 255;
    float v = (k < 128) ? Ws[k * D + n] : Wn[(k - 128) * D + n];
    Wt[idx] = f2bf(v);
}

// Wt2 with inverse col-permutation on the K axis:
//   layer-1 output is stored permuted: h1p[row][(col&15)*8 + (col>>4)] = h1[row][col]
//   so Wt2[n][k'] = W2s[((k'&7)*16 + (k'>>3))][n]  (same for the neigh half)
__global__ void k_prep_w2(const float* __restrict__ Ws, const float* __restrict__ Wn,
                          unsigned short* __restrict__ Wt) {
    int idx = blockIdx.x * 256 + threadIdx.x;  // 32768
    if (idx >= D * 256) return;
    int n = idx >> 8, kp = idx & 255;
    int kk = kp & 127;
    int col = (kk & 7) * 16 + (kk >> 3);
    float v = (kp < 128) ? Ws[col * D + n] : Wn[col * D + n];
    Wt[idx] = f2bf(v);
}

// ---------------- mean aggregation, bf16 gather (16 threads / node) ----------------
__global__ __launch_bounds__(256) void k_agg_bf(const unsigned short* __restrict__ hin,
                                                const int* __restrict__ row_start,
                                                const int* __restrict__ adj,
                                                unsigned short* __restrict__ hout) {
    int node = blockIdx.x * 16 + (threadIdx.x >> 4);
    int sub = threadIdx.x & 15;                      // owns 8 bf16 = 16 B of the row
    if (node >= N_NODES) return;
    int beg = row_start[node], end = row_start[node + 1];
    float acc[8];
#pragma unroll
    for (int i = 0; i < 8; ++i) acc[i] = 0.f;
    int j = beg;
    for (; j + 1 < end; j += 2) {
        int s0 = adj[j], s1 = adj[j + 1];
        u16x8 v0 = *(const u16x8*)(hin + (size_t)s0 * D + sub * 8);
        u16x8 v1 = *(const u16x8*)(hin + (size_t)s1 * D + sub * 8);
#pragma unroll
        for (int i = 0; i < 8; ++i) acc[i] += bf2f(v0[i]) + bf2f(v1[i]);
    }
    if (j < end) {
        int s0 = adj[j];
        u16x8 v0 = *(const u16x8*)(hin + (size_t)s0 * D + sub * 8);
#pragma unroll
        for (int i = 0; i < 8; ++i) acc[i] += bf2f(v0[i]);
    }
    int degn = end - beg;
    float inv = (degn > 0) ? 1.f / (float)degn : 0.f;
    u16x8 p;
#pragma unroll
    for (int i = 0; i < 8; ++i) p[i] = f2bf(acc[i] * inv);
    *(u16x8*)(hout + (size_t)node * D + sub * 8) = p;
}

// ---------------- MFMA GEMM: relu([X0|X1] @ W + b), no LDS ----------------
// 256 thr = 4 waves; wave owns 16 rows x 128 cols; K=256 via 8 k-steps of 32.
// A frag: lane row = l&15, k = 8*(l>>4)+j  (16B contiguous global load)
// B frag from Wt[n][k] (transposed weights): lane col = l&15, same k chunk.
// D frag: col = l&15, row = 4*(l>>4)+reg.
// POOL=0: store bf16, cols permuted c' = (l&15)*8 + ct  (one 16B store per row)
// POOL=1: run-compressed per-graph atomics into gsum (true cols).
template <int POOL>
__global__ __launch_bounds__(256) void k_gemm_mfma(
    const unsigned short* __restrict__ X0, const unsigned short* __restrict__ X1,
    const unsigned short* __restrict__ Wt, const float* __restrict__ bias,
    unsigned short* __restrict__ outp,
    const int* __restrict__ gid, float* __restrict__ gsum) {
    const int tid = threadIdx.x;
    const int wave = tid >> 6, lane = tid & 63;
    const int lm = lane & 15, lg = lane >> 4;
    const int row0 = blockIdx.x * 64 + wave * 16;
    int arow = row0 + lm;
    if (arow > N_NODES - 1) arow = N_NODES - 1;
    const int koff = 8 * lg;

    bf16x8 a[8];
#pragma unroll
    for (int ks = 0; ks < 4; ++ks)
        a[ks] = *(const bf16x8*)(X0 + (size_t)arow * D + ks * 32 + koff);
#pragma unroll
    for (int ks = 0; ks < 4; ++ks)
        a[4 + ks] = *(const bf16x8*)(X1 + (size_t)arow * D + ks * 32 + koff);

    f32x4 acc[8];
#pragma unroll
    for (int i = 0; i < 8; ++i) acc[i] = (f32x4){0.f, 0.f, 0.f, 0.f};

#pragma unroll
    for (int ct = 0; ct < 8; ++ct) {
        const unsigned short* wp = Wt + (size_t)(ct * 16 + lm) * 256 + koff;
        bf16x8 b[8];
#pragma unroll
        for (int ks = 0; ks < 8; ++ks)
            b[ks] = *(const bf16x8*)(wp + ks * 32);
#pragma unroll
        for (int ks = 0; ks < 8; ++ks)
            acc[ct] = __builtin_amdgcn_mfma_f32_16x16x32_bf16(a[ks], b[ks], acc[ct], 0, 0, 0);
    }

    if (POOL == 0) {
#pragma unroll
        for (int r = 0; r < 4; ++r) {
            int row = row0 + 4 * lg + r;
            if (row < N_NODES) {
                u16x8 pk;
#pragma unroll
                for (int ct = 0; ct < 8; ++ct) {
                    float v = acc[ct][r] + bias[ct * 16 + lm];
                    pk[ct] = f2bf(fmaxf(v, 0.f));
                }
                *(u16x8*)(outp + (size_t)row * D + lm * 8) = pk;
            }
        }
    } else {
        int g[4];
#pragma unroll
        for (int r = 0; r < 4; ++r) {
            int row = row0 + 4 * lg + r;
            g[r] = (row < N_NODES) ? gid[row] : -1;
        }
#pragma unroll
        for (int ct = 0; ct < 8; ++ct) {
            int c = ct * 16 + lm;
            float bia = bias[c];
            float run = 0.f; int curg = -1;
#pragma unroll
            for (int r = 0; r < 4; ++r) {
                if (g[r] >= 0) {
                    float v = fmaxf(acc[ct][r] + bia, 0.f);
                    if (g[r] != curg) {
                        if (curg >= 0) atomicAdd(&gsum[curg * D + c], run);
                        curg = g[r]; run = v;
                    } else {
                        run += v;
                    }
                }
            }
            if (curg >= 0) atomicAdd(&gsum[curg * D + c], run);
        }
    }
}

// ---------------- final divide ----------------
__global__ void k_final(const float* __restrict__ gsum, const int* __restrict__ gcnt,
                        float* __restrict__ out) {
    int i = blockIdx.x * blockDim.x + threadIdx.x;
    if (i < NUM_GRAPHS * D) {
        int g = i >> 7;
        int c = gcnt[g];
        out[i] = gsum[i] / (float)(c > 0 ? c : 1);
    }
}

// ---------------- launch ----------------
extern "C" void kernel_launch(void* const* d_in, const int* in_sizes, int n_in,
                              void* d_out, int out_size, void* d_ws, size_t ws_size,
                              hipStream_t stream) {
    const float* h   = (const float*)d_in[0];
    const float* W1s = (const float*)d_in[1];
    const float* W1n = (const float*)d_in[2];
    const float* b1  = (const float*)d_in[3];
    const float* W2s = (const float*)d_in[4];
    const float* W2n = (const float*)d_in[5];
    const float* b2  = (const float*)d_in[6];
    const int* src   = (const int*)d_in[7];
    const int* dst   = (const int*)d_in[8];
    const int* gids  = (const int*)d_in[9];
    float* out = (float*)d_out;
    char* ws = (char*)d_ws;

    size_t off = 0;
    auto alloc = [&](size_t bytes) {
        size_t o = off;
        off = (off + bytes + 255) & ~(size_t)255;
        return o;
    };
    // zeroed region (one memset)
    size_t z0         = off;
    size_t deg_off    = alloc((size_t)N_NODES * 4);
    size_t cursor_off = alloc((size_t)N_NODES * 4);
    size_t gsum_off   = alloc((size_t)NUM_GRAPHS * D * 4);
    size_t bsum_off   = alloc(128 * 4);
    size_t zlen       = off - z0;
    size_t gcnt_off   = alloc((size_t)NUM_GRAPHS * 4);
    size_t rs_off     = alloc((size_t)(N_NODES + 1) * 4);
    size_t adj_off    = alloc((size_t)N_EDGES * 4);
    size_t hb_off     = alloc((size_t)N_NODES * D * 2);   // h bf16
    size_t hn_off     = alloc((size_t)N_NODES * D * 2);   // neigh agg bf16 (reused layer2)
    size_t h1_off     = alloc((size_t)N_NODES * D * 2);   // layer-1 out (permuted) bf16
    size_t wt1_off    = alloc((size_t)D * 256 * 2);
    size_t wt2_off    = alloc((size_t)D * 256 * 2);
    (void)ws_size;

    int*   deg       = (int*)(ws + deg_off);
    int*   cursor    = (int*)(ws + cursor_off);
    int*   gcnt     = (int*)(ws + gcnt_off);
    float* gsum      = (float*)(ws + gsum_off);
    int*   bsum      = (int*)(ws + bsum_off);
    int*   row_start = (int*)(ws + rs_off);
    int*   adj       = (int*)(ws + adj_off);
    unsigned short* hb  = (unsigned short*)(ws + hb_off);
    unsigned short* hn  = (unsigned short*)(ws + hn_off);
    unsigned short* h1p = (unsigned short*)(ws + h1_off);
    unsigned short* Wt1 = (unsigned short*)(ws + wt1_off);
    unsigned short* Wt2 = (unsigned short*)(ws + wt2_off);

    hipMemsetAsync(ws + z0, 0, zlen, stream);

    const int nb_scan = (N_NODES + SCAN_ITEMS - 1) / SCAN_ITEMS;  // 98

    k_edge_deg<<<(N_EDGES + 255) / 256, 256, 0, stream>>>(dst, deg);
    k_gcnt_bs<<<1, 128, 0, stream>>>(gids, gcnt);
    k_scan1<<<nb_scan, 256, 0, stream>>>(deg, bsum);
    k_scan2<<<1, 64, 0, stream>>>(bsum, row_start, nb_scan);
    k_scan3<<<nb_scan, 256, 0, stream>>>(deg, bsum, row_start);
    k_fill<<<(N_EDGES + 255) / 256, 256, 0, stream>>>(src, dst, row_start, cursor, adj);

    k_cast_h<<<(N_NODES * (D / 8) + 255) / 256, 256, 0, stream>>>(h, hb);
    k_prep_w1<<<(D * 256 + 255) / 256, 256, 0, stream>>>(W1s, W1n, Wt1);
    k_prep_w2<<<(D * 256 + 255) / 256, 256, 0, stream>>>(W2s, W2n, Wt2);

    const int gemm_blocks = (N_NODES + 63) / 64;   // 1563
    const int agg_blocks  = (N_NODES + 15) / 16;   // 6250

    // layer 1
    k_agg_bf<<<agg_blocks, 256, 0, stream>>>(hb, row_start, adj, hn);
    k_gemm_mfma<0><<<gemm_blocks, 256, 0, stream>>>(hb, hn, Wt1, b1, h1p, nullptr, nullptr);
    // layer 2 (pool fused into epilogue)
    k_agg_bf<<<agg_blocks, 256, 0, stream>>>(h1p, row_start, adj, hn);
    k_gemm_mfma<1><<<gemm_blocks, 256, 0, stream>>>(h1p, hn, Wt2, b2, nullptr, gids, gsum);

    k_final<<<(NUM_GRAPHS * D + 255) / 256, 256, 0, stream>>>(gsum, gcnt, out);
}

// Round 4
// 429.489 us; speedup vs baseline: 2.4128x; 1.2261x over previous
//
#include <hip/hip_runtime.h>

#define N_NODES   100000
#define N_EDGES   1600000
#define D         128
#define NUM_GRAPHS 128

#define SCAN_ITEMS 1024   // items per scan block (256 thr x 4)

typedef __attribute__((ext_vector_type(8))) short   bf16x8;
typedef __attribute__((ext_vector_type(8))) unsigned short u16x8;
typedef __attribute__((ext_vector_type(4))) float   f32x4;

__device__ __forceinline__ float bf2f(unsigned short v) {
    return __uint_as_float(((unsigned int)v) << 16);
}
__device__ __forceinline__ unsigned short f2bf(float f) {
    unsigned int u = __float_as_uint(f);
    u = (u + 0x7FFFu + ((u >> 16) & 1u)) >> 16;
    return (unsigned short)u;
}

// ---------------- CSR build ----------------

__global__ void k_edge_deg(const int* __restrict__ dst, int* __restrict__ deg) {
    int e = blockIdx.x * blockDim.x + threadIdx.x;
    if (e < N_EDGES) atomicAdd(&deg[dst[e]], 1);
}

// graph_ids is SORTED -> per-graph count via binary search, no atomics.
__global__ void k_gcnt_bs(const int* __restrict__ gid, int* __restrict__ gcnt) {
    int g = threadIdx.x;
    if (g >= NUM_GRAPHS) return;
    int lo = 0, hi = N_NODES;
    while (lo < hi) { int mid = (lo + hi) >> 1; if (gid[mid] < g) lo = mid + 1; else hi = mid; }
    int beg = lo;
    hi = N_NODES;
    while (lo < hi) { int mid = (lo + hi) >> 1; if (gid[mid] < g + 1) lo = mid + 1; else hi = mid; }
    gcnt[g] = lo - beg;
}

__global__ void k_scan1(const int* __restrict__ deg, int* __restrict__ bsum) {
    __shared__ int sh[256];
    int base = blockIdx.x * SCAN_ITEMS + threadIdx.x * 4;
    int s = 0;
#pragma unroll
    for (int i = 0; i < 4; ++i) {
        int idx = base + i;
        if (idx < N_NODES) s += deg[idx];
    }
    sh[threadIdx.x] = s;
    __syncthreads();
    for (int off = 128; off > 0; off >>= 1) {
        if (threadIdx.x < off) sh[threadIdx.x] += sh[threadIdx.x + off];
        __syncthreads();
    }
    if (threadIdx.x == 0) bsum[blockIdx.x] = sh[0];
}

__global__ void k_scan2(int* __restrict__ bsum, int* __restrict__ row_start, int nb) {
    if (threadIdx.x == 0 && blockIdx.x == 0) {
        int run = 0;
        for (int i = 0; i < nb; ++i) { int t = bsum[i]; bsum[i] = run; run += t; }
        row_start[N_NODES] = run;
    }
}

__global__ void k_scan3(const int* __restrict__ deg, const int* __restrict__ bsum,
                        int* __restrict__ row_start) {
    __shared__ int sh[256];
    int t = threadIdx.x;
    int base = blockIdx.x * SCAN_ITEMS + t * 4;
    int v[4]; int s = 0;
#pragma unroll
    for (int i = 0; i < 4; ++i) {
        int idx = base + i;
        v[i] = (idx < N_NODES) ? deg[idx] : 0;
        s += v[i];
    }
    sh[t] = s;
    __syncthreads();
    for (int off = 1; off < 256; off <<= 1) {
        int add = (t >= off) ? sh[t - off] : 0;
        __syncthreads();
        sh[t] += add;
        __syncthreads();
    }
    int excl = ((t > 0) ? sh[t - 1] : 0) + bsum[blockIdx.x];
#pragma unroll
    for (int i = 0; i < 4; ++i) {
        int idx = base + i;
        if (idx < N_NODES) { row_start[idx] = excl; excl += v[i]; }
    }
}

__global__ void k_fill(const int* __restrict__ src, const int* __restrict__ dst,
                       const int* __restrict__ row_start, int* __restrict__ cursor,
                       int* __restrict__ adj) {
    int e = blockIdx.x * blockDim.x + threadIdx.x;
    if (e < N_EDGES) {
        int d = dst[e];
        int pos = atomicAdd(&cursor[d], 1);
        adj[row_start[d] + pos] = src[e];
    }
}

// ---------------- casts / weight prep ----------------

// h fp32 [N,128] -> bf16
__global__ void k_cast_h(const float* __restrict__ h, unsigned short* __restrict__ hb) {
    int i = blockIdx.x * 256 + threadIdx.x;          // one thread = 8 elems
    if (i >= N_NODES * (D / 8)) return;
    const float4* hv = (const float4*)h;
    float4 x = hv[2 * i], y = hv[2 * i + 1];
    u16x8 p;
    p[0] = f2bf(x.x); p[1] = f2bf(x.y); p[2] = f2bf(x.z); p[3] = f2bf(x.w);
    p[4] = f2bf(y.x); p[5] = f2bf(y.y); p[6] = f2bf(y.z); p[7] = f2bf(y.w);
    *(u16x8*)(hb + (size_t)i * 8) = p;
}

// Fragment-linear weight prep:
//   Wtp[((ct*8+ks)*64 + lane)*8 + j] = W[k][n],  n = ct*16+(lane&15),
//   k = ks*32 + 8*(lane>>4) + j.  (k<128 -> Ws, else Wn at k-128)
__global__ void k_prep_w1(const float* __restrict__ Ws, const float* __restrict__ Wn,
                          unsigned short* __restrict__ Wtp) {
    int idx = blockIdx.x * 256 + threadIdx.x;  // 32768
    if (idx >= D * 256) return;
    int j  = idx & 7;
    int l  = (idx >> 3) & 63;
    int fs = idx >> 9;               // ct*8 + ks
    int ct = fs >> 3, ks = fs & 7;
    int n  = ct * 16 + (l & 15);
    int k  = ks * 32 + 8 * (l >> 4) + j;
    float v = (k < 128) ? Ws[k * D + n] : Wn[(k - 128) * D + n];
    Wtp[idx] = f2bf(v);
}

// Same, but layer-1 output columns are stored permuted:
//   h1p[row][(col&15)*8 + (col>>4)] = h1[row][col]
// so the layer-2 K index k' maps to true col = ((k'&7)*16 + (k'>>3)).
__global__ void k_prep_w2(const float* __restrict__ Ws, const float* __restrict__ Wn,
                          unsigned short* __restrict__ Wtp) {
    int idx = blockIdx.x * 256 + threadIdx.x;  // 32768
    if (idx >= D * 256) return;
    int j  = idx & 7;
    int l  = (idx >> 3) & 63;
    int fs = idx >> 9;
    int ct = fs >> 3, ks = fs & 7;
    int n  = ct * 16 + (l & 15);
    int kp = ks * 32 + 8 * (l >> 4) + j;
    int kk = kp & 127;
    int col = (kk & 7) * 16 + (kk >> 3);
    float v = (kp < 128) ? Ws[col * D + n] : Wn[col * D + n];
    Wtp[idx] = f2bf(v);
}

// ---------------- mean aggregation, bf16 gather (16 threads / node) ----------------
__global__ __launch_bounds__(256) void k_agg_bf(const unsigned short* __restrict__ hin,
                                                const int* __restrict__ row_start,
                                                const int* __restrict__ adj,
                                                unsigned short* __restrict__ hout) {
    int node = blockIdx.x * 16 + (threadIdx.x >> 4);
    int sub = threadIdx.x & 15;                      // owns 8 bf16 = 16 B of the row
    if (node >= N_NODES) return;
    int beg = row_start[node], end = row_start[node + 1];
    float acc[8];
#pragma unroll
    for (int i = 0; i < 8; ++i) acc[i] = 0.f;
    int j = beg;
    for (; j + 1 < end; j += 2) {
        int s0 = adj[j], s1 = adj[j + 1];
        u16x8 v0 = *(const u16x8*)(hin + (size_t)s0 * D + sub * 8);
        u16x8 v1 = *(const u16x8*)(hin + (size_t)s1 * D + sub * 8);
#pragma unroll
        for (int i = 0; i < 8; ++i) acc[i] += bf2f(v0[i]) + bf2f(v1[i]);
    }
    if (j < end) {
        int s0 = adj[j];
        u16x8 v0 = *(const u16x8*)(hin + (size_t)s0 * D + sub * 8);
#pragma unroll
        for (int i = 0; i < 8; ++i) acc[i] += bf2f(v0[i]);
    }
    int degn = end - beg;
    float inv = (degn > 0) ? 1.f / (float)degn : 0.f;
    u16x8 p;
#pragma unroll
    for (int i = 0; i < 8; ++i) p[i] = f2bf(acc[i] * inv);
    *(u16x8*)(hout + (size_t)node * D + sub * 8) = p;
}

// ---------------- MFMA GEMM with LDS-staged fragment-linear weights ----------------
// 256 thr = 4 waves; block owns 128 rows (wave w: rows w*32..w*32+31 as 2 row-tiles).
// Wtp (64 KB) staged linearly into LDS; B-frag ds_read_b128 is conflict-free
// (consecutive lanes -> consecutive 16B). A-frags issued before the staging barrier.
// POOL=0: store bf16, cols permuted c' = (l&15)*8 + ct  (one 16B store per row)
// POOL=1: run-compressed per-graph atomics into gsum (true cols).
template <int POOL>
__global__ __launch_bounds__(256) void k_gemm_mfma(
    const unsigned short* __restrict__ X0, const unsigned short* __restrict__ X1,
    const unsigned short* __restrict__ Wtp, const float* __restrict__ bias,
    unsigned short* __restrict__ outp,
    const int* __restrict__ gid, float* __restrict__ gsum) {
    __shared__ unsigned short WS[D * 256];   // 64 KB
    const int tid = threadIdx.x;
    const int wave = tid >> 6, lane = tid & 63;
    const int lm = lane & 15, lg = lane >> 4;
    const int row0 = blockIdx.x * 128 + wave * 32;
    const int koff = 8 * lg;

    // A fragments for 2 row-tiles (issued first; latency hides under staging)
    bf16x8 a[2][8];
#pragma unroll
    for (int t2 = 0; t2 < 2; ++t2) {
        int arow = row0 + t2 * 16 + lm;
        if (arow > N_NODES - 1) arow = N_NODES - 1;
#pragma unroll
        for (int ks = 0; ks < 4; ++ks)
            a[t2][ks] = *(const bf16x8*)(X0 + (size_t)arow * D + ks * 32 + koff);
#pragma unroll
        for (int ks = 0; ks < 4; ++ks)
            a[t2][4 + ks] = *(const bf16x8*)(X1 + (size_t)arow * D + ks * 32 + koff);
    }

    // stage weights -> LDS (linear 64 KB copy)
    {
        const u16x8* g = (const u16x8*)Wtp;
        u16x8* s = (u16x8*)WS;
#pragma unroll
        for (int i = 0; i < 16; ++i) s[i * 256 + tid] = g[i * 256 + tid];
    }
    __syncthreads();

    f32x4 acc[2][8];
#pragma unroll
    for (int t2 = 0; t2 < 2; ++t2)
#pragma unroll
        for (int i = 0; i < 8; ++i) acc[t2][i] = (f32x4){0.f, 0.f, 0.f, 0.f};

#pragma unroll
    for (int ct = 0; ct < 8; ++ct) {
        bf16x8 b[8];
#pragma unroll
        for (int ks = 0; ks < 8; ++ks)
            b[ks] = *(const bf16x8*)&WS[((ct * 8 + ks) * 64 + lane) * 8];
#pragma unroll
        for (int ks = 0; ks < 8; ++ks) {
            acc[0][ct] = __builtin_amdgcn_mfma_f32_16x16x32_bf16(a[0][ks], b[ks], acc[0][ct], 0, 0, 0);
            acc[1][ct] = __builtin_amdgcn_mfma_f32_16x16x32_bf16(a[1][ks], b[ks], acc[1][ct], 0, 0, 0);
        }
    }

#pragma unroll
    for (int t2 = 0; t2 < 2; ++t2) {
        const int trow0 = row0 + t2 * 16;
        if (POOL == 0) {
#pragma unroll
            for (int r = 0; r < 4; ++r) {
                int row = trow0 + 4 * lg + r;
                if (row < N_NODES) {
                    u16x8 pk;
#pragma unroll
                    for (int ct = 0; ct < 8; ++ct) {
                        float v = acc[t2][ct][r] + bias[ct * 16 + lm];
                        pk[ct] = f2bf(fmaxf(v, 0.f));
                    }
                    *(u16x8*)(outp + (size_t)row * D + lm * 8) = pk;
                }
            }
        } else {
            int g[4];
#pragma unroll
            for (int r = 0; r < 4; ++r) {
                int row = trow0 + 4 * lg + r;
                g[r] = (row < N_NODES) ? gid[row] : -1;
            }
#pragma unroll
            for (int ct = 0; ct < 8; ++ct) {
                int c = ct * 16 + lm;
                float bia = bias[c];
                float run = 0.f; int curg = -1;
#pragma unroll
                for (int r = 0; r < 4; ++r) {
                    if (g[r] >= 0) {
                        float v = fmaxf(acc[t2][ct][r] + bia, 0.f);
                        if (g[r] != curg) {
                            if (curg >= 0) atomicAdd(&gsum[curg * D + c], run);
                            curg = g[r]; run = v;
                        } else {
                            run += v;
                        }
                    }
                }
                if (curg >= 0) atomicAdd(&gsum[curg * D + c], run);
            }
        }
    }
}

// ---------------- final divide ----------------
__global__ void k_final(const float* __restrict__ gsum, const int* __restrict__ gcnt,
                        float* __restrict__ out) {
    int i = blockIdx.x * blockDim.x + threadIdx.x;
    if (i < NUM_GRAPHS * D) {
        int g = i >> 7;
        int c = gcnt[g];
        out[i] = gsum[i] / (float)(c > 0 ? c : 1);
    }
}

// ---------------- launch ----------------
extern "C" void kernel_launch(void* const* d_in, const int* in_sizes, int n_in,
                              void* d_out, int out_size, void* d_ws, size_t ws_size,
                              hipStream_t stream) {
    const float* h   = (const float*)d_in[0];
    const float* W1s = (const float*)d_in[1];
    const float* W1n = (const float*)d_in[2];
    const float* b1  = (const float*)d_in[3];
    const float* W2s = (const float*)d_in[4];
    const float* W2n = (const float*)d_in[5];
    const float* b2  = (const float*)d_in[6];
    const int* src   = (const int*)d_in[7];
    const int* dst   = (const int*)d_in[8];
    const int* gids  = (const int*)d_in[9];
    float* out = (float*)d_out;
    char* ws = (char*)d_ws;

    size_t off = 0;
    auto alloc = [&](size_t bytes) {
        size_t o = off;
        off = (off + bytes + 255) & ~(size_t)255;
        return o;
    };
    // zeroed region (one memset)
    size_t z0         = off;
    size_t deg_off    = alloc((size_t)N_NODES * 4);
    size_t cursor_off = alloc((size_t)N_NODES * 4);
    size_t gsum_off   = alloc((size_t)NUM_GRAPHS * D * 4);
    size_t bsum_off   = alloc(128 * 4);
    size_t zlen       = off - z0;
    size_t gcnt_off   = alloc((size_t)NUM_GRAPHS * 4);
    size_t rs_off     = alloc((size_t)(N_NODES + 1) * 4);
    size_t adj_off    = alloc((size_t)N_EDGES * 4);
    size_t hb_off     = alloc((size_t)N_NODES * D * 2);   // h bf16
    size_t hn_off     = alloc((size_t)N_NODES * D * 2);   // neigh agg bf16 (reused layer2)
    size_t h1_off     = alloc((size_t)N_NODES * D * 2);   // layer-1 out (permuted) bf16
    size_t wt1_off    = alloc((size_t)D * 256 * 2);
    size_t wt2_off    = alloc((size_t)D * 256 * 2);
    (void)ws_size;

    int*   deg       = (int*)(ws + deg_off);
    int*   cursor    = (int*)(ws + cursor_off);
    int*   gcnt      = (int*)(ws + gcnt_off);
    float* gsum      = (float*)(ws + gsum_off);
    int*   bsum      = (int*)(ws + bsum_off);
    int*   row_start = (int*)(ws + rs_off);
    int*   adj       = (int*)(ws + adj_off);
    unsigned short* hb  = (unsigned short*)(ws + hb_off);
    unsigned short* hn  = (unsigned short*)(ws + hn_off);
    unsigned short* h1p = (unsigned short*)(ws + h1_off);
    unsigned short* Wt1 = (unsigned short*)(ws + wt1_off);
    unsigned short* Wt2 = (unsigned short*)(ws + wt2_off);

    hipMemsetAsync(ws + z0, 0, zlen, stream);

    const int nb_scan = (N_NODES + SCAN_ITEMS - 1) / SCAN_ITEMS;  // 98

    k_edge_deg<<<(N_EDGES + 255) / 256, 256, 0, stream>>>(dst, deg);
    k_gcnt_bs<<<1, 128, 0, stream>>>(gids, gcnt);
    k_scan1<<<nb_scan, 256, 0, stream>>>(deg, bsum);
    k_scan2<<<1, 64, 0, stream>>>(bsum, row_start, nb_scan);
    k_scan3<<<nb_scan, 256, 0, stream>>>(deg, bsum, row_start);
    k_fill<<<(N_EDGES + 255) / 256, 256, 0, stream>>>(src, dst, row_start, cursor, adj);

    k_cast_h<<<(N_NODES * (D / 8) + 255) / 256, 256, 0, stream>>>(h, hb);
    k_prep_w1<<<(D * 256 + 255) / 256, 256, 0, stream>>>(W1s, W1n, Wt1);
    k_prep_w2<<<(D * 256 + 255) / 256, 256, 0, stream>>>(W2s, W2n, Wt2);

    const int gemm_blocks = (N_NODES + 127) / 128;  // 782
    const int agg_blocks  = (N_NODES + 15) / 16;    // 6250

    // layer 1
    k_agg_bf<<<agg_blocks, 256, 0, stream>>>(hb, row_start, adj, hn);
    k_gemm_mfma<0><<<gemm_blocks, 256, 0, stream>>>(hb, hn, Wt1, b1, h1p, nullptr, nullptr);
    // layer 2 (pool fused into epilogue)
    k_agg_bf<<<agg_blocks, 256, 0, stream>>>(h1p, row_start, adj, hn);
    k_gemm_mfma<1><<<gemm_blocks, 256, 0, stream>>>(h1p, hn, Wt2, b2, nullptr, gids, gsum);

    k_final<<<(NUM_GRAPHS * D + 255) / 256, 256, 0, stream>>>(gsum, gcnt, out);
}

// Round 5
// 289.819 us; speedup vs baseline: 3.5757x; 1.4819x over previous
//
#include <hip/hip_runtime.h>

#define N_NODES   100000
#define N_EDGES   1600000
#define D         128
#define NUM_GRAPHS 128

#define NB          196     // dst buckets (512 nodes each): 99999>>9 = 195
#define BUCKET_NODES 512
#define BUCKET_CAP  10240   // >= bucket edge count w/ huge margin (mean 8163, sd 90)
#define EPB         8192    // edges per binplace block

typedef __attribute__((ext_vector_type(8))) short   bf16x8;
typedef __attribute__((ext_vector_type(8))) unsigned short u16x8;
typedef __attribute__((ext_vector_type(4))) float   f32x4;

__device__ __forceinline__ float bf2f(unsigned short v) {
    return __uint_as_float(((unsigned int)v) << 16);
}
__device__ __forceinline__ unsigned short f2bf(float f) {
    unsigned int u = __float_as_uint(f);
    u = (u + 0x7FFFu + ((u >> 16) & 1u)) >> 16;
    return (unsigned short)u;
}

// ---------------- edge binning: counting-sort into 196 bucket regions ----------------
// Packs (src<<9 | dst&511) into fixed-capacity bucket regions. Per-block LDS staging
// makes global writes coalesced; one global atomic per (block,bucket).
__global__ __launch_bounds__(256) void k_binplace(const int* __restrict__ src,
                                                  const int* __restrict__ dst,
                                                  int* __restrict__ gcur,
                                                  unsigned int* __restrict__ binned) {
    __shared__ unsigned int stag[EPB];       // 32 KB
    __shared__ unsigned char sbk[EPB];       // 8 KB
    __shared__ int hist[NB], lstart[NB], lcur[NB], gclaim[NB];
    __shared__ int scan[256];
    const int t = threadIdx.x;
    const int e0 = blockIdx.x * EPB;

    if (t < NB) hist[t] = 0;
    __syncthreads();

    int pk[32]; int bk[32];
#pragma unroll
    for (int i = 0; i < 32; ++i) {
        int e = e0 + t + 256 * i;
        if (e < N_EDGES) {
            int s = src[e], d = dst[e];
            bk[i] = d >> 9;
            pk[i] = (s << 9) | (d & 511);
            atomicAdd(&hist[bk[i]], 1);
        } else {
            bk[i] = -1; pk[i] = 0;
        }
    }
    __syncthreads();

    // exclusive scan of hist[196] (Hillis-Steele over 256)
    int hv = (t < NB) ? hist[t] : 0;
    scan[t] = hv;
    __syncthreads();
    for (int off = 1; off < 256; off <<= 1) {
        int add = (t >= off) ? scan[t - off] : 0;
        __syncthreads();
        scan[t] += add;
        __syncthreads();
    }
    if (t < NB) {
        int ex = scan[t] - hv;
        lstart[t] = ex;
        lcur[t]   = ex;
        gclaim[t] = atomicAdd(&gcur[t], hv);
    }
    __syncthreads();

    // place into staging, grouped by bucket
#pragma unroll
    for (int i = 0; i < 32; ++i) {
        if (bk[i] >= 0) {
            int p = atomicAdd(&lcur[bk[i]], 1);
            stag[p] = (unsigned int)pk[i];
            sbk[p] = (unsigned char)bk[i];
        }
    }
    __syncthreads();

    const int total = scan[NB - 1];   // inclusive scan at last bucket = valid count
    for (int j = t; j < total; j += 256) {
        int b = sbk[j];
        binned[(size_t)b * BUCKET_CAP + gclaim[b] + (j - lstart[b])] = stag[j];
    }
}

// ---------------- per-bucket CSR finalize: row_start/row_len + adj scatter ----------------
// All scatter writes confined to this bucket's 40KB region -> L2-resident.
__global__ __launch_bounds__(256) void k_fill2(const unsigned int* __restrict__ binned,
                                               const int* __restrict__ gcur,
                                               int* __restrict__ adj,
                                               int* __restrict__ row_start,
                                               int* __restrict__ row_len) {
    __shared__ int hist[BUCKET_NODES], lstart[BUCKET_NODES], lcur[BUCKET_NODES];
    __shared__ int s2[256];
    const int t = threadIdx.x;
    const int b = blockIdx.x;
    const int C = gcur[b];
    const unsigned int* bp = binned + (size_t)b * BUCKET_CAP;

    hist[t] = 0; hist[t + 256] = 0;
    __syncthreads();
    for (int j = t; j < C; j += 256)
        atomicAdd(&hist[bp[j] & 511], 1);
    __syncthreads();

    // exclusive scan of hist[512] via pair-reduction + 256-scan
    int h0 = hist[2 * t], h1 = hist[2 * t + 1];
    int sv = h0 + h1;
    s2[t] = sv;
    __syncthreads();
    for (int off = 1; off < 256; off <<= 1) {
        int add = (t >= off) ? s2[t - off] : 0;
        __syncthreads();
        s2[t] += add;
        __syncthreads();
    }
    int ex = s2[t] - sv;
    lstart[2 * t] = ex;          lcur[2 * t] = ex;
    lstart[2 * t + 1] = ex + h0; lcur[2 * t + 1] = ex + h0;
    __syncthreads();

    for (int dl = t; dl < BUCKET_NODES; dl += 256) {
        int n = b * BUCKET_NODES + dl;
        if (n < N_NODES) {
            row_start[n] = b * BUCKET_CAP + lstart[dl];
            row_len[n]   = hist[dl];
        }
    }

    for (int j = t; j < C; j += 256) {
        unsigned int v = bp[j];
        int dl = v & 511;
        int pos = atomicAdd(&lcur[dl], 1);
        adj[(size_t)b * BUCKET_CAP + pos] = (int)(v >> 9);
    }
}

// graph_ids is SORTED -> per-graph count via binary search, no atomics.
__global__ void k_gcnt_bs(const int* __restrict__ gid, int* __restrict__ gcnt) {
    int g = threadIdx.x;
    if (g >= NUM_GRAPHS) return;
    int lo = 0, hi = N_NODES;
    while (lo < hi) { int mid = (lo + hi) >> 1; if (gid[mid] < g) lo = mid + 1; else hi = mid; }
    int beg = lo;
    hi = N_NODES;
    while (lo < hi) { int mid = (lo + hi) >> 1; if (gid[mid] < g + 1) lo = mid + 1; else hi = mid; }
    gcnt[g] = lo - beg;
}

// ---------------- casts / weight prep ----------------

// h fp32 [N,128] -> bf16
__global__ void k_cast_h(const float* __restrict__ h, unsigned short* __restrict__ hb) {
    int i = blockIdx.x * 256 + threadIdx.x;          // one thread = 8 elems
    if (i >= N_NODES * (D / 8)) return;
    const float4* hv = (const float4*)h;
    float4 x = hv[2 * i], y = hv[2 * i + 1];
    u16x8 p;
    p[0] = f2bf(x.x); p[1] = f2bf(x.y); p[2] = f2bf(x.z); p[3] = f2bf(x.w);
    p[4] = f2bf(y.x); p[5] = f2bf(y.y); p[6] = f2bf(y.z); p[7] = f2bf(y.w);
    *(u16x8*)(hb + (size_t)i * 8) = p;
}

// Fragment-linear weight prep:
//   Wtp[((ct*8+ks)*64 + lane)*8 + j] = W[k][n],  n = ct*16+(lane&15),
//   k = ks*32 + 8*(lane>>4) + j.  (k<128 -> Ws, else Wn at k-128)
__global__ void k_prep_w1(const float* __restrict__ Ws, const float* __restrict__ Wn,
                          unsigned short* __restrict__ Wtp) {
    int idx = blockIdx.x * 256 + threadIdx.x;  // 32768
    if (idx >= D * 256) return;
    int j  = idx & 7;
    int l  = (idx >> 3) & 63;
    int fs = idx >> 9;               // ct*8 + ks
    int ct = fs >> 3, ks = fs & 7;
    int n  = ct * 16 + (l & 15);
    int k  = ks * 32 + 8 * (l >> 4) + j;
    float v = (k < 128) ? Ws[k * D + n] : Wn[(k - 128) * D + n];
    Wtp[idx] = f2bf(v);
}

// Same, but layer-1 output columns are stored permuted:
//   h1p[row][(col&15)*8 + (col>>4)] = h1[row][col]
// so the layer-2 K index k' maps to true col = ((k'&7)*16 + (k'>>3)).
__global__ void k_prep_w2(const float* __restrict__ Ws, const float* __restrict__ Wn,
                          unsigned short* __restrict__ Wtp) {
    int idx = blockIdx.x * 256 + threadIdx.x;  // 32768
    if (idx >= D * 256) return;
    int j  = idx & 7;
    int l  = (idx >> 3) & 63;
    int fs = idx >> 9;
    int ct = fs >> 3, ks = fs & 7;
    int n  = ct * 16 + (l & 15);
    int kp = ks * 32 + 8 * (l >> 4) + j;
    int kk = kp & 127;
    int col = (kk & 7) * 16 + (kk >> 3);
    float v = (kp < 128) ? Ws[col * D + n] : Wn[col * D + n];
    Wtp[idx] = f2bf(v);
}

// ---------------- mean aggregation, bf16 gather (16 threads / node) ----------------
__global__ __launch_bounds__(256) void k_agg_bf(const unsigned short* __restrict__ hin,
                                                const int* __restrict__ row_start,
                                                const int* __restrict__ row_len,
                                                const int* __restrict__ adj,
                                                unsigned short* __restrict__ hout) {
    int node = blockIdx.x * 16 + (threadIdx.x >> 4);
    int sub = threadIdx.x & 15;                      // owns 8 bf16 = 16 B of the row
    if (node >= N_NODES) return;
    int beg = row_start[node];
    int len = row_len[node];
    int end = beg + len;
    float acc[8];
#pragma unroll
    for (int i = 0; i < 8; ++i) acc[i] = 0.f;
    int j = beg;
    for (; j + 1 < end; j += 2) {
        int s0 = adj[j], s1 = adj[j + 1];
        u16x8 v0 = *(const u16x8*)(hin + (size_t)s0 * D + sub * 8);
        u16x8 v1 = *(const u16x8*)(hin + (size_t)s1 * D + sub * 8);
#pragma unroll
        for (int i = 0; i < 8; ++i) acc[i] += bf2f(v0[i]) + bf2f(v1[i]);
    }
    if (j < end) {
        int s0 = adj[j];
        u16x8 v0 = *(const u16x8*)(hin + (size_t)s0 * D + sub * 8);
#pragma unroll
        for (int i = 0; i < 8; ++i) acc[i] += bf2f(v0[i]);
    }
    float inv = (len > 0) ? 1.f / (float)len : 0.f;
    u16x8 p;
#pragma unroll
    for (int i = 0; i < 8; ++i) p[i] = f2bf(acc[i] * inv);
    *(u16x8*)(hout + (size_t)node * D + sub * 8) = p;
}

// ---------------- MFMA GEMM with LDS-staged fragment-linear weights ----------------
template <int POOL>
__global__ __launch_bounds__(256) void k_gemm_mfma(
    const unsigned short* __restrict__ X0, const unsigned short* __restrict__ X1,
    const unsigned short* __restrict__ Wtp, const float* __restrict__ bias,
    unsigned short* __restrict__ outp,
    const int* __restrict__ gid, float* __restrict__ gsum) {
    __shared__ unsigned short WS[D * 256];   // 64 KB
    const int tid = threadIdx.x;
    const int wave = tid >> 6, lane = tid & 63;
    const int lm = lane & 15, lg = lane >> 4;
    const int row0 = blockIdx.x * 128 + wave * 32;
    const int koff = 8 * lg;

    // A fragments for 2 row-tiles (issued first; latency hides under staging)
    bf16x8 a[2][8];
#pragma unroll
    for (int t2 = 0; t2 < 2; ++t2) {
        int arow = row0 + t2 * 16 + lm;
        if (arow > N_NODES - 1) arow = N_NODES - 1;
#pragma unroll
        for (int ks = 0; ks < 4; ++ks)
            a[t2][ks] = *(const bf16x8*)(X0 + (size_t)arow * D + ks * 32 + koff);
#pragma unroll
        for (int ks = 0; ks < 4; ++ks)
            a[t2][4 + ks] = *(const bf16x8*)(X1 + (size_t)arow * D + ks * 32 + koff);
    }

    // stage weights -> LDS (linear 64 KB copy)
    {
        const u16x8* g = (const u16x8*)Wtp;
        u16x8* s = (u16x8*)WS;
#pragma unroll
        for (int i = 0; i < 16; ++i) s[i * 256 + tid] = g[i * 256 + tid];
    }
    __syncthreads();

    f32x4 acc[2][8];
#pragma unroll
    for (int t2 = 0; t2 < 2; ++t2)
#pragma unroll
        for (int i = 0; i < 8; ++i) acc[t2][i] = (f32x4){0.f, 0.f, 0.f, 0.f};

#pragma unroll
    for (int ct = 0; ct < 8; ++ct) {
        bf16x8 b[8];
#pragma unroll
        for (int ks = 0; ks < 8; ++ks)
            b[ks] = *(const bf16x8*)&WS[((ct * 8 + ks) * 64 + lane) * 8];
#pragma unroll
        for (int ks = 0; ks < 8; ++ks) {
            acc[0][ct] = __builtin_amdgcn_mfma_f32_16x16x32_bf16(a[0][ks], b[ks], acc[0][ct], 0, 0, 0);
            acc[1][ct] = __builtin_amdgcn_mfma_f32_16x16x32_bf16(a[1][ks], b[ks], acc[1][ct], 0, 0, 0);
        }
    }

#pragma unroll
    for (int t2 = 0; t2 < 2; ++t2) {
        const int trow0 = row0 + t2 * 16;
        if (POOL == 0) {
#pragma unroll
            for (int r = 0; r < 4; ++r) {
                int row = trow0 + 4 * lg + r;
                if (row < N_NODES) {
                    u16x8 pk;
#pragma unroll
                    for (int ct = 0; ct < 8; ++ct) {
                        float v = acc[t2][ct][r] + bias[ct * 16 + lm];
                        pk[ct] = f2bf(fmaxf(v, 0.f));
                    }
                    *(u16x8*)(outp + (size_t)row * D + lm * 8) = pk;
                }
            }
        } else {
            int g[4];
#pragma unroll
            for (int r = 0; r < 4; ++r) {
                int row = trow0 + 4 * lg + r;
                g[r] = (row < N_NODES) ? gid[row] : -1;
            }
#pragma unroll
            for (int ct = 0; ct < 8; ++ct) {
                int c = ct * 16 + lm;
                float bia = bias[c];
                float run = 0.f; int curg = -1;
#pragma unroll
                for (int r = 0; r < 4; ++r) {
                    if (g[r] >= 0) {
                        float v = fmaxf(acc[t2][ct][r] + bia, 0.f);
                        if (g[r] != curg) {
                            if (curg >= 0) atomicAdd(&gsum[curg * D + c], run);
                            curg = g[r]; run = v;
                        } else {
                            run += v;
                        }
                    }
                }
                if (curg >= 0) atomicAdd(&gsum[curg * D + c], run);
            }
        }
    }
}

// ---------------- final divide ----------------
__global__ void k_final(const float* __restrict__ gsum, const int* __restrict__ gcnt,
                        float* __restrict__ out) {
    int i = blockIdx.x * blockDim.x + threadIdx.x;
    if (i < NUM_GRAPHS * D) {
        int g = i >> 7;
        int c = gcnt[g];
        out[i] = gsum[i] / (float)(c > 0 ? c : 1);
    }
}

// ---------------- launch ----------------
extern "C" void kernel_launch(void* const* d_in, const int* in_sizes, int n_in,
                              void* d_out, int out_size, void* d_ws, size_t ws_size,
                              hipStream_t stream) {
    const float* h   = (const float*)d_in[0];
    const float* W1s = (const float*)d_in[1];
    const float* W1n = (const float*)d_in[2];
    const float* b1  = (const float*)d_in[3];
    const float* W2s = (const float*)d_in[4];
    const float* W2n = (const float*)d_in[5];
    const float* b2  = (const float*)d_in[6];
    const int* src   = (const int*)d_in[7];
    const int* dst   = (const int*)d_in[8];
    const int* gids  = (const int*)d_in[9];
    float* out = (float*)d_out;
    char* ws = (char*)d_ws;

    size_t off = 0;
    auto alloc = [&](size_t bytes) {
        size_t o = off;
        off = (off + bytes + 255) & ~(size_t)255;
        return o;
    };
    // zeroed region (one memset)
    size_t z0         = off;
    size_t gcur_off   = alloc((size_t)NB * 4);
    size_t gsum_off   = alloc((size_t)NUM_GRAPHS * D * 4);
    size_t zlen       = off - z0;
    size_t gcnt_off   = alloc((size_t)NUM_GRAPHS * 4);
    size_t rs_off     = alloc((size_t)N_NODES * 4);
    size_t rl_off     = alloc((size_t)N_NODES * 4);
    size_t bin_off    = alloc((size_t)NB * BUCKET_CAP * 4);
    size_t adj_off    = alloc((size_t)NB * BUCKET_CAP * 4);
    size_t hb_off     = alloc((size_t)N_NODES * D * 2);   // h bf16
    size_t hn_off     = alloc((size_t)N_NODES * D * 2);   // neigh agg bf16 (reused layer2)
    size_t h1_off     = alloc((size_t)N_NODES * D * 2);   // layer-1 out (permuted) bf16
    size_t wt1_off    = alloc((size_t)D * 256 * 2);
    size_t wt2_off    = alloc((size_t)D * 256 * 2);
    (void)ws_size;

    int*   gcur      = (int*)(ws + gcur_off);
    int*   gcnt      = (int*)(ws + gcnt_off);
    float* gsum      = (float*)(ws + gsum_off);
    int*   row_start = (int*)(ws + rs_off);
    int*   row_len   = (int*)(ws + rl_off);
    unsigned int* binned = (unsigned int*)(ws + bin_off);
    int*   adj       = (int*)(ws + adj_off);
    unsigned short* hb  = (unsigned short*)(ws + hb_off);
    unsigned short* hn  = (unsigned short*)(ws + hn_off);
    unsigned short* h1p = (unsigned short*)(ws + h1_off);
    unsigned short* Wt1 = (unsigned short*)(ws + wt1_off);
    unsigned short* Wt2 = (unsigned short*)(ws + wt2_off);

    hipMemsetAsync(ws + z0, 0, zlen, stream);

    const int nbin_blocks = (N_EDGES + EPB - 1) / EPB;   // 196

    k_binplace<<<nbin_blocks, 256, 0, stream>>>(src, dst, gcur, binned);
    k_fill2<<<NB, 256, 0, stream>>>(binned, gcur, adj, row_start, row_len);
    k_gcnt_bs<<<1, 128, 0, stream>>>(gids, gcnt);

    k_cast_h<<<(N_NODES * (D / 8) + 255) / 256, 256, 0, stream>>>(h, hb);
    k_prep_w1<<<(D * 256 + 255) / 256, 256, 0, stream>>>(W1s, W1n, Wt1);
    k_prep_w2<<<(D * 256 + 255) / 256, 256, 0, stream>>>(W2s, W2n, Wt2);

    const int gemm_blocks = (N_NODES + 127) / 128;  // 782
    const int agg_blocks  = (N_NODES + 15) / 16;    // 6250

    // layer 1
    k_agg_bf<<<agg_blocks, 256, 0, stream>>>(hb, row_start, row_len, adj, hn);
    k_gemm_mfma<0><<<gemm_blocks, 256, 0, stream>>>(hb, hn, Wt1, b1, h1p, nullptr, nullptr);
    // layer 2 (pool fused into epilogue)
    k_agg_bf<<<agg_blocks, 256, 0, stream>>>(h1p, row_start, row_len, adj, hn);
    k_gemm_mfma<1><<<gemm_blocks, 256, 0, stream>>>(h1p, hn, Wt2, b2, nullptr, gids, gsum);

    k_final<<<(NUM_GRAPHS * D + 255) / 256, 256, 0, stream>>>(gsum, gcnt, out);
}